// Round 10
// baseline (232.899 us; speedup 1.0000x reference)
//
#include <hip/hip_runtime.h>
#include <math.h>

// ---- problem constants -------------------------------------------------
#define BB   4
#define NN   128
#define NPP  16
#define EEE  1280
#define ESP  1024
#define DD   32
#define CC   16
#define OO   32
#define FIN  80
#define MMM  64
#define TT   3
#define TPB  256    // init block
#define MPB  1024   // mega block

#define MAXDEG_SS 48
#define MAXDEG_SP 192

// ---- workspace layout (floats) ----------------------------------------
constexpr int OFF_S    = 0;
constexpr int OFF_SP   = OFF_S   + BB*NN*DD;
constexpr int OFF_BE   = OFF_SP  + BB*NPP*DD;
constexpr int OFF_BSP  = OFF_BE  + BB*EEE*CC;
constexpr int OFF_BPS  = OFF_BSP + BB*ESP*CC;
constexpr int OFF_PRJ  = OFF_BPS + BB*ESP*CC;      // 3 write-once buffers (one/step)
constexpr int P_SASS = 0;
constexpr int P_SBSS = P_SASS + BB*NN*OO;
constexpr int P_SBPS = P_SBSS + BB*NN*OO;
constexpr int P_SASP = P_SBPS + BB*NN*OO;
constexpr int P_PAPS = P_SASP + BB*NN*OO;
constexpr int P_PBSP = P_PAPS + BB*NPP*OO;
constexpr int PRJ_SZ = P_PBSP + BB*NPP*OO;
constexpr int OFF_POOL = OFF_PRJ + 3*PRJ_SZ;
constexpr int OFF_CSR  = OFF_POOL + BB*MMM;
// int layout (relative to OFF_CSR):
constexpr int SS_CNT  = 0;
constexpr int PS_CNT  = SS_CNT + NN;
constexpr int SP_CNT  = PS_CNT + NN;
constexpr int TICKET  = SP_CNT + NPP;               // 272
constexpr int SS_PAIR = 274;
constexpr int PS_PAIR = SS_PAIR + NN*MAXDEG_SS*2;
constexpr int SP_PAIR = PS_PAIR + NN*MAXDEG_SS*2;
constexpr int BAR0    = ((SP_PAIR + NPP*MAXDEG_SP*2 + 31)/32)*32;
constexpr int BAR_STRIDE = 576;
constexpr int BAR_INTS   = 2*BAR_STRIDE;

// agent write-through store (plain store with coherence flags, no RMW)
#define ASTORE(p,v) __hip_atomic_store((p), (v), __ATOMIC_RELAXED, __HIP_MEMORY_SCOPE_AGENT)

// pure coherent read: bypasses L1/L2 (sc0 sc1), reads the coherence point.
// NOT an RMW -> no write traffic, no serialization at the MALL.
__device__ __forceinline__ int coh_load_i(const int* p) {
    int v;
    asm volatile("global_load_dword %0, %1, off sc0 sc1\n\ts_waitcnt vmcnt(0)"
                 : "=v"(v) : "v"(p) : "memory");
    return v;
}
__device__ __forceinline__ float coh_load_f(const float* p) {
    float v;
    asm volatile("global_load_dword %0, %1, off sc0 sc1\n\ts_waitcnt vmcnt(0)"
                 : "=v"(v) : "v"(p) : "memory");
    return v;
}

__device__ __forceinline__ float lrelu(float x) { return x > 0.f ? x : 0.01f * x; }

__device__ __forceinline__ float dot16r(const float* ef, const float* we) {
    float4 f0 = *(const float4*)(ef);
    float4 f1 = *(const float4*)(ef + 4);
    float4 f2 = *(const float4*)(ef + 8);
    float4 f3 = *(const float4*)(ef + 12);
    return f0.x*we[ 0] + f0.y*we[ 1] + f0.z*we[ 2] + f0.w*we[ 3]
         + f1.x*we[ 4] + f1.y*we[ 5] + f1.z*we[ 6] + f1.w*we[ 7]
         + f2.x*we[ 8] + f2.y*we[ 9] + f2.z*we[10] + f2.w*we[11]
         + f3.x*we[12] + f3.y*we[13] + f3.z*we[14] + f3.w*we[15];
}

__device__ __forceinline__ float red32(float r) {
#pragma unroll
    for (int mm = 16; mm > 0; mm >>= 1) r += __shfl_xor(r, mm, 32);
    return r;
}

__device__ __forceinline__ void edge_embed(float d, const float* W, const float* bvec, float* out) {
    float g[CC];
#pragma unroll
    for (int c = 0; c < CC; ++c) {
        float mu = (10.0f / 15.0f) * (float)c;
        float z = d - mu;
        g[c] = expf(-z * z);
    }
#pragma unroll
    for (int j = 0; j < CC; ++j) {
        float a = bvec[j];
#pragma unroll
        for (int c = 0; c < CC; ++c) a += g[c] * W[c * CC + j];
        out[j] = lrelu(a);
    }
}

// wave-ballot CSR build; stores (edge, sender) pairs. Deterministic.
__device__ __forceinline__ void csr_wave(const int* recv, const int* send, int E, int r,
                                         int* cnt, int2* pair, int maxdeg, int lane) {
    int base = 0;
    for (int c = 0; c < E; c += 64) {
        const int e = c + lane;
        const bool m = (recv[e] == r);
        const unsigned long long mask = __ballot(m);
        if (m) {
            const int pos = base + __popcll(mask & ((1ull << lane) - 1ull));
            if (pos < maxdeg) pair[pos] = make_int2(e, send[e]);
        }
        base += (int)__popcll(mask);
    }
    if (lane == 0) cnt[r] = base < maxdeg ? base : maxdeg;
}

// RMW-free fence-free grid barrier. Data visibility comes from the
// write-once + write-through + never-cached-read protocol, not from fences.
__device__ __forceinline__ void arrive_and_wait(int* base) {
    const int grp = (int)blockIdx.x & 15;
    int p = __hip_atomic_fetch_add(base + grp*32, 1, __ATOMIC_RELAXED, __HIP_MEMORY_SCOPE_AGENT);
    if (p == 15) {    // 256 blocks / 16 groups
        int q2 = __hip_atomic_fetch_add(base + 512, 1, __ATOMIC_RELAXED, __HIP_MEMORY_SCOPE_AGENT);
        if (q2 == 15)
            __hip_atomic_store(base + 544, 1, __ATOMIC_RELAXED, __HIP_MEMORY_SCOPE_AGENT);
    }
    while (coh_load_i(base + 544) == 0)
        __builtin_amdgcn_s_sleep(32);   // ~2048 cyc backoff: low poll pressure
}

// ---- K0: init + barrier-zero -------------------------------------------
__global__ __launch_bounds__(TPB) void k_init(
    const float* sites, const float* bonds, const float* sites_p,
    const float* bonds_sp, const float* bonds_ps,
    const int* idx1, const int* idx2, const int* idx1_ps, const int* idx2_ps,
    const int* idx1_sp, const int* idx2_sp,
    const float* se_W, const float* se_b, const float* sep_W, const float* sep_b,
    const float* ee_W, const float* ee_b, const float* eep_W, const float* eep_b,
    const float* eqW1_ss, const float* eqW2_ss,
    const float* eqW1_ps, const float* eqW2_ps,
    const float* eqW1_sp, const float* eqW2_sp,
    float* ws)
{
    __shared__ float smem[4416];
    const int blk = blockIdx.x;
    const int tid = threadIdx.x;
    int* csr = (int*)(ws + OFF_CSR);

    if (blk == 0 && tid == 0) csr[TICKET] = 0;
    if (blk == 141) for (int i = tid; i < BAR_INTS; i += TPB) csr[BAR0 + i] = 0;

    // part A: zero pool + edge-feature embeddings
    if (blk < 253) {
        const int totalA = BB*MMM + BB*EEE + BB*ESP + BB*ESP;
        for (int i = blk*TPB + tid; i < totalA; i += 253*TPB) {
            int r = i;
            if (r < BB*MMM) { ws[OFF_POOL + r] = 0.f; continue; }
            r -= BB*MMM;
            if (r < BB*EEE) { edge_embed(bonds[r],    ee_W,  ee_b,  ws + OFF_BE  + r*CC); continue; }
            r -= BB*EEE;
            if (r < BB*ESP) { edge_embed(bonds_sp[r], eep_W, eep_b, ws + OFF_BSP + r*CC); continue; }
            r -= BB*ESP;
            edge_embed(bonds_ps[r], eep_W, eep_b, ws + OFF_BPS + r*CC);
        }
    }
    // part B: node embeddings + t=0 projections (buffer 0)
    if (blk < 72) {
        float* prj0 = ws + OFF_PRJ;
        const int el = tid >> 5, o = tid & 31;
        float* sP   = smem;
        float* sRow = smem + 4160;
        if (blk < 64) {
            const int g = blk*8 + el;
            float x = sites[g];
            float v0 = lrelu(x * se_W[o] + se_b[o]);
            ws[OFF_S + g*DD + o] = v0;
            sRow[el*32 + o] = v0;
            for (int i2 = tid; i2 < 4096; i2 += TPB) {
                int m = i2 >> 10, j = i2 & 1023, d = j >> 5, oo = j & 31;
                int row = (m == 1 || m == 2) ? (DD + d) : d;
                float wv;
                if (m < 2)      wv = eqW1_ss[row*OO + oo] + eqW2_ss[row*OO + oo];
                else if (m==2)  wv = eqW1_ps[row*OO + oo] + eqW2_ps[row*OO + oo];
                else            wv = eqW1_sp[row*OO + oo] + eqW2_sp[row*OO + oo];
                sP[i2] = wv;
            }
            __syncthreads();
            float p0=0.f,p1=0.f,p2=0.f,p3=0.f;
#pragma unroll
            for (int d = 0; d < 32; ++d) {
                float sv = sRow[el*32 + d];
                p0 += sv * sP[        d*32 + o];
                p1 += sv * sP[1024 +  d*32 + o];
                p2 += sv * sP[2048 +  d*32 + o];
                p3 += sv * sP[3072 +  d*32 + o];
            }
            prj0[P_SASS + g*OO + o] = p0;
            prj0[P_SBSS + g*OO + o] = p1;
            prj0[P_SBPS + g*OO + o] = p2;
            prj0[P_SASP + g*OO + o] = p3;
        } else {
            const int g = (blk-64)*8 + el;
            float x0 = sites_p[g*2], x1 = sites_p[g*2+1];
            float v0 = lrelu(x0 * sep_W[o] + x1 * sep_W[DD + o] + sep_b[o]);
            ws[OFF_SP + g*DD + o] = v0;
            sRow[el*32 + o] = v0;
            for (int i2 = tid; i2 < 2048; i2 += TPB) {
                int m = i2 >> 10, j = i2 & 1023, d = j >> 5, oo = j & 31;
                int row = (m == 0) ? d : (DD + d);
                float wv;
                if (m == 0) wv = eqW1_ps[row*OO + oo] + eqW2_ps[row*OO + oo];
                else        wv = eqW1_sp[row*OO + oo] + eqW2_sp[row*OO + oo];
                sP[i2] = wv;
            }
            __syncthreads();
            float p0=0.f,p1=0.f;
#pragma unroll
            for (int d = 0; d < 32; ++d) {
                float sv = sRow[el*32 + d];
                p0 += sv * sP[        d*32 + o];
                p1 += sv * sP[1024 +  d*32 + o];
            }
            prj0[P_PAPS + g*OO + o] = p0;
            prj0[P_PBSP + g*OO + o] = p1;
        }
    }
    // part C: wave-ballot CSR pair build
    if (blk >= 72 && blk < 140) {
        const int widx = (blk - 72) * 4 + (tid >> 6);
        const int lane = tid & 63;
        if (widx < NN) {
            csr_wave(idx2, idx1, EEE, widx, csr + SS_CNT,
                     (int2*)(csr + SS_PAIR) + widx*MAXDEG_SS, MAXDEG_SS, lane);
        } else if (widx < 2*NN) {
            const int r = widx - NN;
            csr_wave(idx2_ps, idx1_ps, ESP, r, csr + PS_CNT,
                     (int2*)(csr + PS_PAIR) + r*MAXDEG_SS, MAXDEG_SS, lane);
        } else if (widx < 2*NN + NPP) {
            const int r = widx - 2*NN;
            csr_wave(idx2_sp, idx1_sp, ESP, r, csr + SP_CNT,
                     (int2*)(csr + SP_PAIR) + r*MAXDEG_SP, MAXDEG_SP, lane);
        }
    }
}

// ---- K1: persistent mega kernel ----------------------------------------
// 256 blocks x 1024. Block owns site receivers g=blk*2, blk*2+1; blocks
// 0..63 also own pore receiver pg=blk. Projection buffer P[t] is write-once
// (agent write-through stores), read with plain cached loads (first read
// misses -> fetches current data from the coherence point).
__global__ __launch_bounds__(MPB, 4) void k_mega(
    const float* eqW1_ss, const float* eqW2_ss, const float* eqb_ss, const float* aw_ss, const float* ab_ss,
    const float* eqW1_ps, const float* eqW2_ps, const float* eqb_ps, const float* aw_ps, const float* ab_ps,
    const float* eqW1_sp, const float* eqW2_sp, const float* eqb_sp, const float* aw_sp, const float* ab_sp,
    const float* nuW1, const float* nub1, const float* nuW2, const float* nub2,
    const float* nupW1, const float* nupb1, const float* nupW2, const float* nupb2,
    const float* p1W, const float* p1b,
    const float* p2aW, const float* p2ab, const float* p2bW, const float* p2bb,
    const float* p3W, const float* p3b,
    float* ws, float* out)
{
    __shared__ float sRed[1024];
    __shared__ float sRedP[1024];
    __shared__ float sH[192];
    __shared__ float sPH[96];
    __shared__ float sU[64], sPU[32];
    __shared__ float sSnew[64], sPnew[32];
    __shared__ float sHx[256], sHy[256], sHz[256];
    __shared__ int sWin;

    const int tid = threadIdx.x, blk = blockIdx.x;
    const int slot = tid >> 5, o = tid & 31;
    const bool haspore = (blk < 64);
    int* csr = (int*)(ws + OFF_CSR);
    int* bar = csr + BAR0;

    for (int t = 0; t < TT; ++t) {
        const float* PRJ  = ws + OFF_PRJ + t * PRJ_SZ;          // written before this step
        float*       PRJn = ws + OFF_PRJ + (t+1) * PRJ_SZ;      // written for next step

        // ---------- site edge phase ----------
        {
            const int rsel = slot >> 4, s16 = slot & 15;
            const bool is_ss = s16 < 8;
            const int q = s16 & 7;
            const int g = blk*2 + rsel, b = g >> 7, n = g & 127;
            const float* w1p = is_ss ? eqW1_ss : eqW1_ps;
            const float* w2p = is_ss ? eqW2_ss : eqW2_ps;
            const float* wa = w1p + t*FIN*OO + 2*DD*OO + o;
            const float* wb = w2p + t*FIN*OO + 2*DD*OO + o;
            float we[16];
#pragma unroll
            for (int c = 0; c < 16; ++c) we[c] = wa[c*OO] + wb[c*OO];
            const float bias = (is_ss ? eqb_ss : eqb_ps)[t*OO + o];
            const float awo  = (is_ss ? aw_ss  : aw_ps )[t*OO + o];
            const float abv  = (is_ss ? ab_ss  : ab_ps )[t];
            const float sb   = PRJ[(is_ss ? P_SBSS : P_SBPS) + g*OO + o];
            const float* SAb = is_ss ? (PRJ + P_SASS + b*(NN*OO))
                                     : (PRJ + P_PAPS + b*(NPP*OO));
            const float* EFb = is_ss ? (ws + OFF_BE  + b*(EEE*CC))
                                     : (ws + OFF_BPS + b*(ESP*CC));
            const int cnt = is_ss ? csr[SS_CNT + n] : csr[PS_CNT + n];
            const int2* lst = is_ss ? ((const int2*)(csr + SS_PAIR) + n*MAXDEG_SS)
                                    : ((const int2*)(csr + PS_PAIR) + n*MAXDEG_SS);
            float acc = 0.f;
            for (int k = q; k < cnt; k += 8) {
                const int2 es = lst[k];
                float a = bias + sb + SAb[es.y*OO + o] + dot16r(EFb + es.x*CC, we);
                float u = lrelu(a);
                float rr = red32(u * awo);
                acc += u / (1.f + expf(-(rr + abv)));
            }
            sRed[slot*32 + o] = acc;
        }
        // ---------- pore edge phase (blocks 0..63) ----------
        if (haspore) {
            const int pg = blk, pb = pg >> 4, pp = pg & 15;
            const float* wa = eqW1_sp + t*FIN*OO + 2*DD*OO + o;
            const float* wb = eqW2_sp + t*FIN*OO + 2*DD*OO + o;
            float weP[16];
#pragma unroll
            for (int c = 0; c < 16; ++c) weP[c] = wa[c*OO] + wb[c*OO];
            const float bias = eqb_sp[t*OO + o];
            const float awo  = aw_sp[t*OO + o];
            const float abv  = ab_sp[t];
            const float sb   = PRJ[P_PBSP + pg*OO + o];
            const float* SAp = PRJ + P_SASP + pb*(NN*OO);
            const float* EFp = ws + OFF_BSP + pb*(ESP*CC);
            const int cnt = csr[SP_CNT + pp];
            const int2* lst = (const int2*)(csr + SP_PAIR) + pp*MAXDEG_SP;
            float acc = 0.f;
            for (int k = slot; k < cnt; k += 32) {
                const int2 es = lst[k];
                float a = bias + sb + SAp[es.y*OO + o] + dot16r(EFp + es.x*CC, weP);
                float u = lrelu(a);
                float rr = red32(u * awo);
                acc += u / (1.f + expf(-(rr + abv)));
            }
            sRedP[slot*32 + o] = acc;
        }
        __syncthreads();

        // ---------- node updates ----------
        if (tid < 64) {
            const int r2 = tid >> 5, oo = tid & 31;
            float mss = 0.f, mps = 0.f;
#pragma unroll
            for (int j = 0; j < 8; ++j)  mss += sRed[(r2*16 + j)*32 + oo];
#pragma unroll
            for (int j = 8; j < 16; ++j) mps += sRed[(r2*16 + j)*32 + oo];
            sH[r2*96 + oo]      = ws[OFF_S + (blk*2 + r2)*DD + oo];
            sH[r2*96 + 32 + oo] = mss;
            sH[r2*96 + 64 + oo] = mps;
        } else if (tid < 96 && haspore) {
            const int oo = tid & 31;
            float mp = 0.f;
#pragma unroll
            for (int j = 0; j < 32; ++j) mp += sRedP[j*32 + oo];
            sPH[oo]      = ws[OFF_SP + blk*DD + oo];
            sPH[32 + oo] = mp;
        }
        __syncthreads();
        if (tid < 64) {
            const int r2 = tid >> 5, oo = tid & 31;
            const float* W1 = nuW1 + t*(96*32);
            float a = nub1[t*32 + oo];
#pragma unroll
            for (int f = 0; f < 96; ++f) a += sH[r2*96 + f] * W1[f*32 + oo];
            sU[r2*32 + oo] = lrelu(a);
        } else if (tid < 96 && haspore) {
            const int oo = tid & 31;
            const float* W1 = nupW1 + t*(64*32);
            float a = nupb1[t*32 + oo];
#pragma unroll
            for (int f = 0; f < 64; ++f) a += sPH[f] * W1[f*32 + oo];
            sPU[oo] = lrelu(a);
        }
        __syncthreads();
        if (tid < 64) {
            const int r2 = tid >> 5, oo = tid & 31;
            const float* W2 = nuW2 + t*(32*32);
            float a = nub2[t*32 + oo];
#pragma unroll
            for (int k2 = 0; k2 < 32; ++k2) a += sU[r2*32 + k2] * W2[k2*32 + oo];
            const float snew = sH[r2*96 + oo] + lrelu(a);
            ws[OFF_S + (blk*2 + r2)*DD + oo] = snew;   // block-local: plain
            sSnew[r2*32 + oo] = snew;
        } else if (tid < 96 && haspore) {
            const int oo = tid & 31;
            const float* W2 = nupW2 + t*(32*32);
            float a = nupb2[t*32 + oo];
#pragma unroll
            for (int k2 = 0; k2 < 32; ++k2) a += sPU[k2] * W2[k2*32 + oo];
            const float snew = sPH[oo] + lrelu(a);
            ws[OFF_SP + blk*DD + oo] = snew;
            sPnew[oo] = snew;
        }
        __syncthreads();

        if (t < TT-1) {
            // next-step projections -> P[t+1] (agent write-through)
            if (tid < 256) {
                const int tn = t + 1;
                const int m = tid >> 6, r2 = (tid >> 5) & 1, oo = tid & 31;
                const int g2 = blk*2 + r2;
                const float *w1m, *w2m; float* dst;
                if (m == 0)      { w1m = eqW1_ss + tn*FIN*OO;         w2m = eqW2_ss + tn*FIN*OO;         dst = PRJn + P_SASS; }
                else if (m == 1) { w1m = eqW1_ss + tn*FIN*OO + DD*OO; w2m = eqW2_ss + tn*FIN*OO + DD*OO; dst = PRJn + P_SBSS; }
                else if (m == 2) { w1m = eqW1_ps + tn*FIN*OO + DD*OO; w2m = eqW2_ps + tn*FIN*OO + DD*OO; dst = PRJn + P_SBPS; }
                else             { w1m = eqW1_sp + tn*FIN*OO;         w2m = eqW2_sp + tn*FIN*OO;         dst = PRJn + P_SASP; }
                float a = 0.f;
#pragma unroll
                for (int d = 0; d < 32; ++d) a += sSnew[r2*32 + d] * (w1m[d*OO + oo] + w2m[d*OO + oo]);
                ASTORE(&dst[g2*OO + oo], a);
            } else if (tid < 320 && haspore) {
                const int tn = t + 1;
                const int m = (tid - 256) >> 5, oo = tid & 31;
                const float *w1m, *w2m; float* dst;
                if (m == 0) { w1m = eqW1_ps + tn*FIN*OO;         w2m = eqW2_ps + tn*FIN*OO;         dst = PRJn + P_PAPS; }
                else        { w1m = eqW1_sp + tn*FIN*OO + DD*OO; w2m = eqW2_sp + tn*FIN*OO + DD*OO; dst = PRJn + P_PBSP; }
                float a = 0.f;
#pragma unroll
                for (int d = 0; d < 32; ++d) a += sPnew[d] * (w1m[d*OO + oo] + w2m[d*OO + oo]);
                ASTORE(&dst[blk*OO + oo], a);
            }
            __syncthreads();            // drains vmcnt: write-through stores at MALL
            if (tid == 0) arrive_and_wait(bar + t*BAR_STRIDE);
            __syncthreads();
        } else {
            // pooling + ticket + head
            if (tid < 128) {
                const int r2 = tid >> 6, mm = tid & 63;
                const int g2 = blk*2 + r2, b2 = g2 >> 7;
                float a = p1b[mm];
#pragma unroll
                for (int d = 0; d < 32; ++d) a += sSnew[r2*32 + d] * p1W[d*MMM + mm];
                atomicAdd(&ws[OFF_POOL + b2*MMM + mm], lrelu(a));
            }
            __syncthreads();            // drains pool atomics
            if (tid == 0) {
                int p = __hip_atomic_fetch_add(csr + TICKET, 1, __ATOMIC_RELAXED, __HIP_MEMORY_SCOPE_AGENT);
                sWin = (p == 255) ? 1 : 0;
            }
            __syncthreads();
            if (sWin) {
                if (tid < 256) sHx[tid] = coh_load_f(&ws[OFF_POOL + tid]);
                __syncthreads();
                if (tid < 256) {
                    const int b2 = tid >> 6, mm = tid & 63;
                    float a = p2ab[mm];
#pragma unroll
                    for (int k = 0; k < MMM; ++k) a += sHx[b2*64 + k] * p2aW[k*MMM + mm];
                    sHy[tid] = lrelu(a);
                }
                __syncthreads();
                if (tid < 256) {
                    const int b2 = tid >> 6, mm = tid & 63;
                    float a = p2bb[mm];
#pragma unroll
                    for (int k = 0; k < MMM; ++k) a += sHy[b2*64 + k] * p2bW[k*MMM + mm];
                    sHz[tid] = lrelu(a);
                }
                __syncthreads();
                if (tid < BB) {
                    float acc2 = p3b[0];
#pragma unroll
                    for (int k = 0; k < MMM; ++k) acc2 += sHz[tid*64 + k] * p3W[k];
                    out[tid] = acc2;
                }
            }
        }
    }
}

// ---- launch ------------------------------------------------------------
extern "C" void kernel_launch(void* const* d_in, const int* in_sizes, int n_in,
                              void* d_out, int out_size, void* d_ws, size_t ws_size,
                              hipStream_t stream) {
    (void)in_sizes; (void)n_in; (void)out_size; (void)ws_size;
    const float* sites    = (const float*)d_in[0];
    const float* bonds    = (const float*)d_in[1];
    const float* sites_p  = (const float*)d_in[2];
    const float* bonds_sp = (const float*)d_in[3];
    const float* bonds_ps = (const float*)d_in[4];
    const int* idx1    = (const int*)d_in[5];
    const int* idx2    = (const int*)d_in[6];
    const int* idx1_sp = (const int*)d_in[7];
    const int* idx2_sp = (const int*)d_in[8];
    const int* idx1_ps = (const int*)d_in[9];
    const int* idx2_ps = (const int*)d_in[10];
    const float* se_W  = (const float*)d_in[11];
    const float* se_b  = (const float*)d_in[12];
    const float* sep_W = (const float*)d_in[13];
    const float* sep_b = (const float*)d_in[14];
    const float* ee_W  = (const float*)d_in[15];
    const float* ee_b  = (const float*)d_in[16];
    const float* eep_W = (const float*)d_in[17];
    const float* eep_b = (const float*)d_in[18];
    const float* eqW1_ss = (const float*)d_in[19];
    const float* eqW2_ss = (const float*)d_in[20];
    const float* eqb_ss  = (const float*)d_in[21];
    const float* aw_ss   = (const float*)d_in[22];
    const float* ab_ss   = (const float*)d_in[23];
    const float* eqW1_ps = (const float*)d_in[24];
    const float* eqW2_ps = (const float*)d_in[25];
    const float* eqb_ps  = (const float*)d_in[26];
    const float* aw_ps   = (const float*)d_in[27];
    const float* ab_ps   = (const float*)d_in[28];
    const float* eqW1_sp = (const float*)d_in[29];
    const float* eqW2_sp = (const float*)d_in[30];
    const float* eqb_sp  = (const float*)d_in[31];
    const float* aw_sp   = (const float*)d_in[32];
    const float* ab_sp   = (const float*)d_in[33];
    const float* nuW1  = (const float*)d_in[34];
    const float* nub1  = (const float*)d_in[35];
    const float* nuW2  = (const float*)d_in[36];
    const float* nub2  = (const float*)d_in[37];
    const float* nupW1 = (const float*)d_in[38];
    const float* nupb1 = (const float*)d_in[39];
    const float* nupW2 = (const float*)d_in[40];
    const float* nupb2 = (const float*)d_in[41];
    const float* p1W  = (const float*)d_in[42];
    const float* p1b  = (const float*)d_in[43];
    const float* p2aW = (const float*)d_in[44];
    const float* p2ab = (const float*)d_in[45];
    const float* p2bW = (const float*)d_in[46];
    const float* p2bb = (const float*)d_in[47];
    const float* p3W  = (const float*)d_in[48];
    const float* p3b  = (const float*)d_in[49];

    float* ws  = (float*)d_ws;
    float* out = (float*)d_out;

    k_init<<<256, TPB, 0, stream>>>(sites, bonds, sites_p, bonds_sp, bonds_ps,
                                    idx1, idx2, idx1_ps, idx2_ps, idx1_sp, idx2_sp,
                                    se_W, se_b, sep_W, sep_b, ee_W, ee_b, eep_W, eep_b,
                                    eqW1_ss, eqW2_ss, eqW1_ps, eqW2_ps, eqW1_sp, eqW2_sp, ws);
    k_mega<<<256, MPB, 0, stream>>>(
        eqW1_ss, eqW2_ss, eqb_ss, aw_ss, ab_ss,
        eqW1_ps, eqW2_ps, eqb_ps, aw_ps, ab_ps,
        eqW1_sp, eqW2_sp, eqb_sp, aw_sp, ab_sp,
        nuW1, nub1, nuW2, nub2, nupW1, nupb1, nupW2, nupb2,
        p1W, p1b, p2aW, p2ab, p2bW, p2bb, p3W, p3b,
        ws, out);
}

// Round 11
// 106.671 us; speedup vs baseline: 2.1833x; 2.1833x over previous
//
#include <hip/hip_runtime.h>
#include <math.h>

// ---- problem constants -------------------------------------------------
#define BB   4
#define NN   128
#define NPP  16
#define EEE  1280
#define ESP  1024
#define DD   32
#define CC   16
#define OO   32
#define FIN  80
#define MMM  64
#define TT   3
#define TPB  256

#define MAXDEG_SS 48
#define MAXDEG_SP 192

// ---- workspace layout (floats) ----------------------------------------
constexpr int OFF_S    = 0;                        // site states   [B*N*32]
constexpr int OFF_SP   = OFF_S   + BB*NN*DD;       // pore states
constexpr int OFF_BE   = OFF_SP  + BB*NPP*DD;      // ss edge feats (written t=0)
constexpr int OFF_BSP  = OFF_BE  + BB*EEE*CC;      // sp edge feats
constexpr int OFF_BPS  = OFF_BSP + BB*ESP*CC;      // ps edge feats
constexpr int OFF_PRJ  = OFF_BPS + BB*ESP*CC;      // 2x parity proj buffers
constexpr int P_SASS = 0;
constexpr int P_SBSS = P_SASS + BB*NN*OO;
constexpr int P_SBPS = P_SBSS + BB*NN*OO;
constexpr int P_SASP = P_SBPS + BB*NN*OO;
constexpr int P_PAPS = P_SASP + BB*NN*OO;
constexpr int P_PBSP = P_PAPS + BB*NPP*OO;
constexpr int PRJ_SZ = P_PBSP + BB*NPP*OO;
constexpr int OFF_POOL = OFF_PRJ + 2*PRJ_SZ;       // pooled [B*M]
constexpr int OFF_CSR  = OFF_POOL + BB*MMM;        // int region
// CSR int offsets (relative, R7 layout):
constexpr int SS_CNT  = 0;                         // [N]
constexpr int SS_LIST = SS_CNT + NN;               // [N*48]
constexpr int PS_CNT  = SS_LIST + NN*MAXDEG_SS;    // [N]
constexpr int PS_LIST = PS_CNT + NN;               // [N*48]
constexpr int SP_CNT  = PS_LIST + NN*MAXDEG_SS;    // [Np]
constexpr int SP_LIST = SP_CNT + NPP;              // [Np*192]
constexpr int CSR_INTS = SP_LIST + NPP*MAXDEG_SP;
constexpr int TICKET   = CSR_INTS;

__device__ __forceinline__ float lrelu(float x) { return x > 0.f ? x : 0.01f * x; }

__device__ __forceinline__ float dot16(const float* ef, const float* sWe, int o) {
    float4 f0 = *(const float4*)(ef);
    float4 f1 = *(const float4*)(ef + 4);
    float4 f2 = *(const float4*)(ef + 8);
    float4 f3 = *(const float4*)(ef + 12);
    return f0.x*sWe[ 0*32+o] + f0.y*sWe[ 1*32+o] + f0.z*sWe[ 2*32+o] + f0.w*sWe[ 3*32+o]
         + f1.x*sWe[ 4*32+o] + f1.y*sWe[ 5*32+o] + f1.z*sWe[ 6*32+o] + f1.w*sWe[ 7*32+o]
         + f2.x*sWe[ 8*32+o] + f2.y*sWe[ 9*32+o] + f2.z*sWe[10*32+o] + f2.w*sWe[11*32+o]
         + f3.x*sWe[12*32+o] + f3.y*sWe[13*32+o] + f3.z*sWe[14*32+o] + f3.w*sWe[15*32+o];
}

__device__ __forceinline__ float red32(float r) {
#pragma unroll
    for (int mm = 16; mm > 0; mm >>= 1) r += __shfl_xor(r, mm, 32);
    return r;
}

// ---- K0: step 0, fully self-sufficient (no init kernel) ----------------
// grid = 320 x 256: blocks 0..255 site receivers (2 each), 256..319 pores.
// Each block ballot-scans its own edge lists, stages weights in LDS,
// computes embeddings/projections/edge-feats on the fly, aggregates,
// updates its nodes, writes PRJ (parity 1), EF, and (b==0) the CSR.
__global__ __launch_bounds__(TPB) void k_step0(
    const float* sites, const float* bonds, const float* sites_p,
    const float* bonds_sp, const float* bonds_ps,
    const int* idx1, const int* idx2, const int* idx1_ps, const int* idx2_ps,
    const int* idx1_sp, const int* idx2_sp,
    const float* se_W, const float* se_b, const float* sep_W, const float* sep_b,
    const float* ee_W, const float* ee_b, const float* eep_W, const float* eep_b,
    const float* eqW1_ss, const float* eqW2_ss, const float* eqb_ss, const float* aw_ss, const float* ab_ss,
    const float* eqW1_ps, const float* eqW2_ps, const float* eqb_ps, const float* aw_ps, const float* ab_ps,
    const float* eqW1_sp, const float* eqW2_sp, const float* eqb_sp, const float* aw_sp, const float* ab_sp,
    const float* nuW1, const float* nub1, const float* nuW2, const float* nub2,
    const float* nupW1, const float* nupb1, const float* nupW2, const float* nupb2,
    float* ws)
{
    __shared__ float sWA1[1024], sWA2[1024], sWB1[1024], sWB2[1024];
    __shared__ float sWE1[512], sWE2[512];
    __shared__ float sEWa[272], sEWb[272];   // eeW+eeb / eepW+eepb
    __shared__ float sEmb[160];              // seW,seb,sepW0,sepW1,sepb
    __shared__ int2  sLany[192];             // site: 4 lists x 48; pore: 1 x 192
    __shared__ int   sCnt[4];
    __shared__ float sRed[512], sH[192], sU[64], sSnew[64];

    const int tid = threadIdx.x, blk = blockIdx.x;
    const int slot = tid >> 5, o = tid & 31;
    int* csr = (int*)(ws + OFF_CSR);
    float* PRJn = ws + OFF_PRJ + 1 * PRJ_SZ;   // t=0 writes parity-1 buffer

    if (blk < 256) {
        // ================= site block: receivers g=blk*2, blk*2+1 ========
        const int b  = (blk*2) >> 7;
        const int n0 = (blk*2) & 127;
        // --- ballot scans: wave w -> list w (w0: ss n0, w1: ss n1, w2: ps n0, w3: ps n1)
        {
            const int w = tid >> 6, lane = tid & 63;
            const int nw = n0 + (w & 1);
            const int* recvp = (w < 2) ? idx2 : idx2_ps;
            const int* sendp = (w < 2) ? idx1 : idx1_ps;
            const int Ew     = (w < 2) ? EEE : ESP;
            int2* ldst = sLany + w*48;
            int*  gcnt = csr + ((w < 2) ? SS_CNT : PS_CNT);
            int*  glst = csr + ((w < 2) ? (SS_LIST + nw*MAXDEG_SS) : (PS_LIST + nw*MAXDEG_SS));
            int base = 0;
            for (int c = 0; c < Ew; c += 64) {
                const int e = c + lane;
                const bool m = (recvp[e] == nw);
                const unsigned long long mask = __ballot(m);
                if (m) {
                    const int pos = base + __popcll(mask & ((1ull << lane) - 1ull));
                    if (pos < MAXDEG_SS) {
                        ldst[pos] = make_int2(e, sendp[e]);
                        if (b == 0) glst[pos] = e;
                    }
                }
                base += (int)__popcll(mask);
            }
            if (lane == 0) {
                int cc = base < MAXDEG_SS ? base : MAXDEG_SS;
                sCnt[w] = cc;
                if (b == 0) gcnt[nw] = cc;
            }
        }
        // --- stage weights (t=0 slices; rows 0..31=A, 32..63=B, 64..79=E)
        for (int i = tid; i < 1024; i += TPB) {
            sWA1[i] = eqW1_ss[i]        + eqW2_ss[i];
            sWB1[i] = eqW1_ss[1024 + i] + eqW2_ss[1024 + i];
            sWA2[i] = eqW1_ps[i]        + eqW2_ps[i];
            sWB2[i] = eqW1_ps[1024 + i] + eqW2_ps[1024 + i];
        }
        for (int i = tid; i < 512; i += TPB) {
            sWE1[i] = eqW1_ss[2048 + i] + eqW2_ss[2048 + i];
            sWE2[i] = eqW1_ps[2048 + i] + eqW2_ps[2048 + i];
        }
        if (tid < 256) { sEWa[tid] = ee_W[tid]; sEWb[tid] = eep_W[tid]; }
        if (tid < 16)  { sEWa[256+tid] = ee_b[tid]; sEWb[256+tid] = eep_b[tid]; }
        if (tid < 32) {
            sEmb[tid]      = se_W[tid];
            sEmb[32+tid]   = se_b[tid];
            sEmb[64+tid]   = sep_W[tid];
            sEmb[96+tid]   = sep_W[32+tid];
            sEmb[128+tid]  = sep_b[tid];
        }
        __syncthreads();

        // --- edge phase (R7 grouping: r=slot>>2 receiver, q=slot&3)
        const int r = slot >> 2, q = slot & 3;
        const int g = blk*2 + r;
        float acc_ss = 0.f, acc_ps = 0.f;
        {
            const float x_r = sites[g];
            float sb_ss = 0.f, sb_ps = 0.f;
#pragma unroll
            for (int d = 0; d < 32; ++d) {
                float s0d = lrelu(x_r*sEmb[d] + sEmb[32+d]);
                sb_ss += s0d * sWB1[d*32 + o];
                sb_ps += s0d * sWB2[d*32 + o];
            }
            // ss stream
            {
                const float bias = eqb_ss[o], awo = aw_ss[o], abv = ab_ss[0];
                const int cnt = sCnt[r];
                const int2* lst = sLany + r*48;
                for (int k = q; k < cnt; k += 4) {
                    const int2 es = lst[k];
                    const float xs = sites[b*NN + es.y];
                    float SA = 0.f;
#pragma unroll
                    for (int d = 0; d < 32; ++d)
                        SA += lrelu(xs*sEmb[d] + sEmb[32+d]) * sWA1[d*32 + o];
                    const float bv = bonds[b*EEE + es.x];
                    float gg[16];
#pragma unroll
                    for (int c = 0; c < 16; ++c) { float z = bv - (10.f/15.f)*c; gg[c] = expf(-z*z); }
                    float edot = 0.f, myef = 0.f;
#pragma unroll
                    for (int j = 0; j < 16; ++j) {
                        float ej = sEWa[256+j];
#pragma unroll
                        for (int c = 0; c < 16; ++c) ej += gg[c]*sEWa[c*16+j];
                        ej = lrelu(ej);
                        edot += ej * sWE1[j*32 + o];
                        if (o == j) myef = ej;
                    }
                    if (o < 16) ws[OFF_BE + (b*EEE + es.x)*CC + o] = myef;
                    float u = lrelu(bias + sb_ss + SA + edot);
                    float rr = red32(u * awo);
                    acc_ss += u / (1.f + expf(-(rr + abv)));
                }
            }
            // ps stream (pore senders)
            {
                const float bias = eqb_ps[o], awo = aw_ps[o], abv = ab_ps[0];
                const int cnt = sCnt[2 + r];
                const int2* lst = sLany + (2 + r)*48;
                for (int k = q; k < cnt; k += 4) {
                    const int2 es = lst[k];
                    const float xp0 = sites_p[(b*NPP + es.y)*2];
                    const float xp1 = sites_p[(b*NPP + es.y)*2 + 1];
                    float SA = 0.f;
#pragma unroll
                    for (int d = 0; d < 32; ++d)
                        SA += lrelu(xp0*sEmb[64+d] + xp1*sEmb[96+d] + sEmb[128+d]) * sWA2[d*32 + o];
                    const float bv = bonds_ps[b*ESP + es.x];
                    float gg[16];
#pragma unroll
                    for (int c = 0; c < 16; ++c) { float z = bv - (10.f/15.f)*c; gg[c] = expf(-z*z); }
                    float edot = 0.f, myef = 0.f;
#pragma unroll
                    for (int j = 0; j < 16; ++j) {
                        float ej = sEWb[256+j];
#pragma unroll
                        for (int c = 0; c < 16; ++c) ej += gg[c]*sEWb[c*16+j];
                        ej = lrelu(ej);
                        edot += ej * sWE2[j*32 + o];
                        if (o == j) myef = ej;
                    }
                    if (o < 16) ws[OFF_BPS + (b*ESP + es.x)*CC + o] = myef;
                    float u = lrelu(bias + sb_ps + SA + edot);
                    float rr = red32(u * awo);
                    acc_ps += u / (1.f + expf(-(rr + abv)));
                }
            }
        }
        sRed[slot*64 + o]      = acc_ss;
        sRed[slot*64 + 32 + o] = acc_ps;
        if (tid < 64) {
            const int e2 = tid >> 5, oo = tid & 31;
            sH[e2*96 + oo] = lrelu(sites[blk*2 + e2]*sEmb[oo] + sEmb[32+oo]);
        }
        __syncthreads();
        if (tid < 128) {
            const int r2 = tid >> 6, c = tid & 63;
            sH[r2*96 + 32 + c] = sRed[(r2*4  )*64 + c] + sRed[(r2*4+1)*64 + c]
                               + sRed[(r2*4+2)*64 + c] + sRed[(r2*4+3)*64 + c];
        }
        __syncthreads();
        if (tid < 64) {
            const int r2 = tid >> 5, oo = tid & 31;
            float a = nub1[oo];
#pragma unroll
            for (int f = 0; f < 96; ++f) a += sH[r2*96 + f] * nuW1[f*32 + oo];
            sU[r2*32 + oo] = lrelu(a);
        }
        __syncthreads();
        if (tid < 64) {
            const int r2 = tid >> 5, oo = tid & 31;
            float a = nub2[oo];
#pragma unroll
            for (int k2 = 0; k2 < 32; ++k2) a += sU[r2*32 + k2] * nuW2[k2*32 + oo];
            const float snew = sH[r2*96 + oo] + lrelu(a);
            ws[OFF_S + (blk*2 + r2)*DD + oo] = snew;
            sSnew[r2*32 + oo] = snew;
        }
        __syncthreads();
        // epilogue: projections for step 1 (parity-1 buffer)
        {
            const int r2 = slot >> 2, m = slot & 3;
            const int g2 = blk*2 + r2;
            const float *w1m, *w2m; float* dst;
            if (m == 0)      { w1m = eqW1_ss + 1*FIN*OO;         w2m = eqW2_ss + 1*FIN*OO;         dst = PRJn + P_SASS; }
            else if (m == 1) { w1m = eqW1_ss + 1*FIN*OO + DD*OO; w2m = eqW2_ss + 1*FIN*OO + DD*OO; dst = PRJn + P_SBSS; }
            else if (m == 2) { w1m = eqW1_ps + 1*FIN*OO + DD*OO; w2m = eqW2_ps + 1*FIN*OO + DD*OO; dst = PRJn + P_SBPS; }
            else             { w1m = eqW1_sp + 1*FIN*OO;         w2m = eqW2_sp + 1*FIN*OO;         dst = PRJn + P_SASP; }
            float a = 0.f;
#pragma unroll
            for (int d = 0; d < 32; ++d) a += sSnew[r2*32 + d] * (w1m[d*OO + o] + w2m[d*OO + o]);
            dst[g2*OO + o] = a;
        }
    } else {
        // ================= pore block: receiver pg=blk-256 ================
        const int pg = blk - 256, b = pg >> 4, p = pg & 15;
        // --- ballot scan (wave 0)
        if (tid < 64) {
            const int lane = tid;
            int base = 0;
            for (int c = 0; c < ESP; c += 64) {
                const int e = c + lane;
                const bool m = (idx2_sp[e] == p);
                const unsigned long long mask = __ballot(m);
                if (m) {
                    const int pos = base + __popcll(mask & ((1ull << lane) - 1ull));
                    if (pos < MAXDEG_SP) {
                        sLany[pos] = make_int2(e, idx1_sp[e]);
                        if (b == 0) csr[SP_LIST + p*MAXDEG_SP + pos] = e;
                    }
                }
                base += (int)__popcll(mask);
            }
            if (lane == 0) {
                int cc = base < MAXDEG_SP ? base : MAXDEG_SP;
                sCnt[0] = cc;
                if (b == 0) csr[SP_CNT + p] = cc;
            }
        }
        // --- stage sp weights
        for (int i = tid; i < 1024; i += TPB) {
            sWA1[i] = eqW1_sp[i]        + eqW2_sp[i];
            sWB1[i] = eqW1_sp[1024 + i] + eqW2_sp[1024 + i];
        }
        for (int i = tid; i < 512; i += TPB)
            sWE1[i] = eqW1_sp[2048 + i] + eqW2_sp[2048 + i];
        if (tid < 256) sEWa[tid] = eep_W[tid];
        if (tid < 16)  sEWa[256+tid] = eep_b[tid];
        if (tid < 32) {
            sEmb[tid]      = se_W[tid];
            sEmb[32+tid]   = se_b[tid];
            sEmb[64+tid]   = sep_W[tid];
            sEmb[96+tid]   = sep_W[32+tid];
            sEmb[128+tid]  = sep_b[tid];
        }
        __syncthreads();

        const float xp0 = sites_p[pg*2], xp1 = sites_p[pg*2 + 1];
        float sb = 0.f;
#pragma unroll
        for (int d = 0; d < 32; ++d)
            sb += lrelu(xp0*sEmb[64+d] + xp1*sEmb[96+d] + sEmb[128+d]) * sWB1[d*32 + o];
        const float bias = eqb_sp[o], awo = aw_sp[o], abv = ab_sp[0];
        const int cnt = sCnt[0];
        float acc = 0.f;
        for (int k = slot; k < cnt; k += 8) {
            const int2 es = sLany[k];
            const float xs = sites[b*NN + es.y];
            float SA = 0.f;
#pragma unroll
            for (int d = 0; d < 32; ++d)
                SA += lrelu(xs*sEmb[d] + sEmb[32+d]) * sWA1[d*32 + o];
            const float bv = bonds_sp[b*ESP + es.x];
            float gg[16];
#pragma unroll
            for (int c = 0; c < 16; ++c) { float z = bv - (10.f/15.f)*c; gg[c] = expf(-z*z); }
            float edot = 0.f, myef = 0.f;
#pragma unroll
            for (int j = 0; j < 16; ++j) {
                float ej = sEWa[256+j];
#pragma unroll
                for (int c = 0; c < 16; ++c) ej += gg[c]*sEWa[c*16+j];
                ej = lrelu(ej);
                edot += ej * sWE1[j*32 + o];
                if (o == j) myef = ej;
            }
            if (o < 16) ws[OFF_BSP + (b*ESP + es.x)*CC + o] = myef;
            float u = lrelu(bias + sb + SA + edot);
            float rr = red32(u * awo);
            acc += u / (1.f + expf(-(rr + abv)));
        }
        sRed[slot*32 + o] = acc;
        if (tid < 32) sH[tid] = lrelu(xp0*sEmb[64+tid] + xp1*sEmb[96+tid] + sEmb[128+tid]);
        __syncthreads();
        if (tid < 32) {
            float mv = 0.f;
#pragma unroll
            for (int s2 = 0; s2 < 8; ++s2) mv += sRed[s2*32 + tid];
            sH[32 + tid] = mv;
        }
        __syncthreads();
        if (tid < 32) {
            float a = nupb1[tid];
#pragma unroll
            for (int f = 0; f < 64; ++f) a += sH[f] * nupW1[f*32 + tid];
            sU[tid] = lrelu(a);
        }
        __syncthreads();
        if (tid < 32) {
            float a = nupb2[tid];
#pragma unroll
            for (int k2 = 0; k2 < 32; ++k2) a += sU[k2] * nupW2[k2*32 + tid];
            const float snew = sH[tid] + lrelu(a);
            ws[OFF_SP + pg*DD + tid] = snew;
            sSnew[tid] = snew;
        }
        __syncthreads();
        if (tid < 64) {
            const int m = slot, oo = tid & 31;   // slot 0,1
            const float *w1m, *w2m; float* dst;
            if (m == 0) { w1m = eqW1_ps + 1*FIN*OO;         w2m = eqW2_ps + 1*FIN*OO;         dst = PRJn + P_PAPS; }
            else        { w1m = eqW1_sp + 1*FIN*OO + DD*OO; w2m = eqW2_sp + 1*FIN*OO + DD*OO; dst = PRJn + P_PBSP; }
            float a = 0.f;
#pragma unroll
            for (int d = 0; d < 32; ++d) a += sSnew[d] * (w1m[d*OO + oo] + w2m[d*OO + oo]);
            dst[pg*OO + oo] = a;
        }
    }
}

// ---- K1: steps 1..2, verbatim R7 k_step (+pool/ticket zero at t==1) -----
__global__ __launch_bounds__(TPB) void k_step(
    const float* eqW1_ss, const float* eqW2_ss, const float* eqb_ss, const float* aw_ss, const float* ab_ss,
    const float* eqW1_ps, const float* eqW2_ps, const float* eqb_ps, const float* aw_ps, const float* ab_ps,
    const float* eqW1_sp, const float* eqW2_sp, const float* eqb_sp, const float* aw_sp, const float* ab_sp,
    const int* idx1, const int* idx1_ps, const int* idx1_sp,
    const float* nuW1, const float* nub1, const float* nuW2, const float* nub2,
    const float* nupW1, const float* nupb1, const float* nupW2, const float* nupb2,
    const float* p1W, const float* p1b,
    const float* p2aW, const float* p2ab, const float* p2bW, const float* p2bb,
    const float* p3W, const float* p3b,
    float* ws, float* out, int t)
{
    __shared__ float sWe1[512], sWe2[512], sRed[512], sH[192], sU[64], sSnew[64];
    __shared__ int sWin;
    const int tid = threadIdx.x, blk = blockIdx.x;
    const int slot = tid >> 5, o = tid & 31;
    const int par = t & 1;
    const float* PRJ  = ws + OFF_PRJ + par * PRJ_SZ;
    float*       PRJn = ws + OFF_PRJ + (par ^ 1) * PRJ_SZ;
    const int* csr = (const int*)(ws + OFF_CSR);

    if (t == 1 && blk == 0) {          // prep pool+ticket for t==2
        ws[OFF_POOL + tid] = 0.f;
        if (tid == 0) ((int*)(ws + OFF_CSR))[TICKET] = 0;
    }

    if (blk < 256) {
        // ======== site receivers: 2 per block, 4 lane-groups each ========
        const int r = slot >> 2, q = slot & 3;
        for (int i = tid; i < 512; i += TPB) {
            sWe1[i] = eqW1_ss[t*FIN*OO + 2*DD*OO + i] + eqW2_ss[t*FIN*OO + 2*DD*OO + i];
            sWe2[i] = eqW1_ps[t*FIN*OO + 2*DD*OO + i] + eqW2_ps[t*FIN*OO + 2*DD*OO + i];
        }
        __syncthreads();
        const int g = blk*2 + r, b = g >> 7, n = g & 127;
        const float bias_ss = eqb_ss[t*OO+o], awo_ss = aw_ss[t*OO+o], abs_ss = ab_ss[t];
        const float bias_ps = eqb_ps[t*OO+o], awo_ps = aw_ps[t*OO+o], abs_ps = ab_ps[t];
        const float sb_ss = PRJ[P_SBSS + g*OO + o];
        const float sb_ps = PRJ[P_SBPS + g*OO + o];
        const float* SAss = PRJ + P_SASS + b*(NN*OO);
        const float* PAps = PRJ + P_PAPS + b*(NPP*OO);
        const float* BEb  = ws + OFF_BE  + b*(EEE*CC);
        const float* BPSb = ws + OFF_BPS + b*(ESP*CC);
        float acc_ss = 0.f, acc_ps = 0.f;
        {
            const int cnt = csr[SS_CNT + n];
            const int* lst = csr + SS_LIST + n*MAXDEG_SS;
            for (int k = q; k < cnt; k += 4) {
                const int e = lst[k];
                const int s1 = idx1[e];
                float a = bias_ss + sb_ss + SAss[s1*OO + o] + dot16(BEb + e*CC, sWe1, o);
                float u = lrelu(a);
                float rr = red32(u * awo_ss);
                acc_ss += u / (1.f + expf(-(rr + abs_ss)));
            }
        }
        {
            const int cnt = csr[PS_CNT + n];
            const int* lst = csr + PS_LIST + n*MAXDEG_SS;
            for (int k = q; k < cnt; k += 4) {
                const int e = lst[k];
                const int s1 = idx1_ps[e];
                float a = bias_ps + sb_ps + PAps[s1*OO + o] + dot16(BPSb + e*CC, sWe2, o);
                float u = lrelu(a);
                float rr = red32(u * awo_ps);
                acc_ps += u / (1.f + expf(-(rr + abs_ps)));
            }
        }
        sRed[slot*64 + o]      = acc_ss;
        sRed[slot*64 + 32 + o] = acc_ps;
        if (tid < 64) sH[(tid>>5)*96 + (tid&31)] = ws[OFF_S + (blk*2 + (tid>>5))*DD + (tid&31)];
        __syncthreads();
        if (tid < 128) {
            const int r2 = tid >> 6, c = tid & 63;
            sH[r2*96 + 32 + c] = sRed[(r2*4  )*64 + c] + sRed[(r2*4+1)*64 + c]
                               + sRed[(r2*4+2)*64 + c] + sRed[(r2*4+3)*64 + c];
        }
        __syncthreads();
        if (tid < 64) {
            const int r2 = tid >> 5, oo = tid & 31;
            const float* W1 = nuW1 + t*(96*32);
            float a = nub1[t*32 + oo];
#pragma unroll
            for (int f = 0; f < 96; ++f) a += sH[r2*96 + f] * W1[f*32 + oo];
            sU[r2*32 + oo] = lrelu(a);
        }
        __syncthreads();
        if (tid < 64) {
            const int r2 = tid >> 5, oo = tid & 31;
            const float* W2 = nuW2 + t*(32*32);
            float a = nub2[t*32 + oo];
#pragma unroll
            for (int k2 = 0; k2 < 32; ++k2) a += sU[r2*32 + k2] * W2[k2*32 + oo];
            const float snew = sH[r2*96 + oo] + lrelu(a);
            ws[OFF_S + (blk*2 + r2)*DD + oo] = snew;
            sSnew[r2*32 + oo] = snew;
        }
        __syncthreads();
        if (t < TT-1) {
            const int r2 = slot >> 2, m = slot & 3;
            const int g2 = blk*2 + r2;
            const int tn = t + 1;
            const float *w1m, *w2m; float* dst;
            if (m == 0)      { w1m = eqW1_ss + tn*FIN*OO;         w2m = eqW2_ss + tn*FIN*OO;         dst = PRJn + P_SASS; }
            else if (m == 1) { w1m = eqW1_ss + tn*FIN*OO + DD*OO; w2m = eqW2_ss + tn*FIN*OO + DD*OO; dst = PRJn + P_SBSS; }
            else if (m == 2) { w1m = eqW1_ps + tn*FIN*OO + DD*OO; w2m = eqW2_ps + tn*FIN*OO + DD*OO; dst = PRJn + P_SBPS; }
            else             { w1m = eqW1_sp + tn*FIN*OO;         w2m = eqW2_sp + tn*FIN*OO;         dst = PRJn + P_SASP; }
            float a = 0.f;
#pragma unroll
            for (int d = 0; d < 32; ++d) a += sSnew[r2*32 + d] * (w1m[d*OO + o] + w2m[d*OO + o]);
            dst[g2*OO + o] = a;
        } else {
            if (tid < 128) {
                const int r2 = tid >> 6, mm = tid & 63;
                const int g2 = blk*2 + r2, b2 = g2 >> 7;
                float a = p1b[mm];
#pragma unroll
                for (int d = 0; d < 32; ++d) a += sSnew[r2*32 + d] * p1W[d*MMM + mm];
                atomicAdd(&ws[OFF_POOL + b2*MMM + mm], lrelu(a));
            }
            __syncthreads();
            if (tid == 0) {
                int* ticket = (int*)(ws + OFF_CSR) + TICKET;
                int p = __hip_atomic_fetch_add(ticket, 1, __ATOMIC_ACQ_REL, __HIP_MEMORY_SCOPE_AGENT);
                sWin = (p == 255) ? 1 : 0;
            }
            __syncthreads();
            if (sWin) {
                float* sx = sWe1;
                float* sy = sWe2;
                float* sz = sRed;
                sx[tid] = __hip_atomic_load(&ws[OFF_POOL + tid], __ATOMIC_RELAXED, __HIP_MEMORY_SCOPE_AGENT);
                __syncthreads();
                const int b2 = tid >> 6, mm = tid & 63;
                float a = p2ab[mm];
#pragma unroll
                for (int k = 0; k < MMM; ++k) a += sx[b2*64 + k] * p2aW[k*MMM + mm];
                sy[tid] = lrelu(a);
                __syncthreads();
                a = p2bb[mm];
#pragma unroll
                for (int k = 0; k < MMM; ++k) a += sy[b2*64 + k] * p2bW[k*MMM + mm];
                sz[tid] = lrelu(a);
                __syncthreads();
                if (tid < BB) {
                    float acc = p3b[0];
#pragma unroll
                    for (int k = 0; k < MMM; ++k) acc += sz[tid*64 + k] * p3W[k];
                    out[tid] = acc;
                }
            }
        }
    } else {
        // ======== pore receivers: 1 per block, 8 lane-groups ========
        for (int i = tid; i < 512; i += TPB)
            sWe1[i] = eqW1_sp[t*FIN*OO + 2*DD*OO + i] + eqW2_sp[t*FIN*OO + 2*DD*OO + i];
        __syncthreads();
        const int g = blk - 256, b = g >> 4, p = g & 15;
        const float bias_sp = eqb_sp[t*OO+o], awo_sp = aw_sp[t*OO+o], abs_sp = ab_sp[t];
        const float sb_sp = PRJ[P_PBSP + g*OO + o];
        const float* SAsp = PRJ + P_SASP + b*(NN*OO);
        const float* BSPb = ws + OFF_BSP + b*(ESP*CC);
        float acc_sp = 0.f;
        {
            const int cnt = csr[SP_CNT + p];
            const int* lst = csr + SP_LIST + p*MAXDEG_SP;
            for (int k = slot; k < cnt; k += 8) {
                const int e = lst[k];
                const int s1 = idx1_sp[e];
                float a = bias_sp + sb_sp + SAsp[s1*OO + o] + dot16(BSPb + e*CC, sWe1, o);
                float u = lrelu(a);
                float rr = red32(u * awo_sp);
                acc_sp += u / (1.f + expf(-(rr + abs_sp)));
            }
        }
        sRed[slot*32 + o] = acc_sp;
        if (tid < 32) sH[tid] = ws[OFF_SP + g*DD + tid];
        __syncthreads();
        if (tid < 32) {
            float mv = 0.f;
#pragma unroll
            for (int s2 = 0; s2 < 8; ++s2) mv += sRed[s2*32 + tid];
            sH[32 + tid] = mv;
        }
        __syncthreads();
        if (tid < 32) {
            const float* W1 = nupW1 + t*(64*32);
            float a = nupb1[t*32 + tid];
#pragma unroll
            for (int f = 0; f < 64; ++f) a += sH[f] * W1[f*32 + tid];
            sU[tid] = lrelu(a);
        }
        __syncthreads();
        if (tid < 32) {
            const float* W2 = nupW2 + t*(32*32);
            float a = nupb2[t*32 + tid];
#pragma unroll
            for (int k2 = 0; k2 < 32; ++k2) a += sU[k2] * W2[k2*32 + tid];
            const float snew = sH[tid] + lrelu(a);
            ws[OFF_SP + g*DD + tid] = snew;
            sSnew[tid] = snew;
        }
        __syncthreads();
        if (t < TT-1 && tid < 64) {
            const int tn = t + 1;
            const int m = tid >> 5, oo = tid & 31;
            const float *w1m, *w2m; float* dst;
            if (m == 0) { w1m = eqW1_ps + tn*FIN*OO;         w2m = eqW2_ps + tn*FIN*OO;         dst = PRJn + P_PAPS; }
            else        { w1m = eqW1_sp + tn*FIN*OO + DD*OO; w2m = eqW2_sp + tn*FIN*OO + DD*OO; dst = PRJn + P_PBSP; }
            float a = 0.f;
#pragma unroll
            for (int d = 0; d < 32; ++d) a += sSnew[d] * (w1m[d*OO + oo] + w2m[d*OO + oo]);
            dst[g*OO + oo] = a;
        }
    }
}

// ---- launch ------------------------------------------------------------
extern "C" void kernel_launch(void* const* d_in, const int* in_sizes, int n_in,
                              void* d_out, int out_size, void* d_ws, size_t ws_size,
                              hipStream_t stream) {
    (void)in_sizes; (void)n_in; (void)out_size; (void)ws_size;
    const float* sites    = (const float*)d_in[0];
    const float* bonds    = (const float*)d_in[1];
    const float* sites_p  = (const float*)d_in[2];
    const float* bonds_sp = (const float*)d_in[3];
    const float* bonds_ps = (const float*)d_in[4];
    const int* idx1    = (const int*)d_in[5];
    const int* idx2    = (const int*)d_in[6];
    const int* idx1_sp = (const int*)d_in[7];
    const int* idx2_sp = (const int*)d_in[8];
    const int* idx1_ps = (const int*)d_in[9];
    const int* idx2_ps = (const int*)d_in[10];
    const float* se_W  = (const float*)d_in[11];
    const float* se_b  = (const float*)d_in[12];
    const float* sep_W = (const float*)d_in[13];
    const float* sep_b = (const float*)d_in[14];
    const float* ee_W  = (const float*)d_in[15];
    const float* ee_b  = (const float*)d_in[16];
    const float* eep_W = (const float*)d_in[17];
    const float* eep_b = (const float*)d_in[18];
    const float* eqW1_ss = (const float*)d_in[19];
    const float* eqW2_ss = (const float*)d_in[20];
    const float* eqb_ss  = (const float*)d_in[21];
    const float* aw_ss   = (const float*)d_in[22];
    const float* ab_ss   = (const float*)d_in[23];
    const float* eqW1_ps = (const float*)d_in[24];
    const float* eqW2_ps = (const float*)d_in[25];
    const float* eqb_ps  = (const float*)d_in[26];
    const float* aw_ps   = (const float*)d_in[27];
    const float* ab_ps   = (const float*)d_in[28];
    const float* eqW1_sp = (const float*)d_in[29];
    const float* eqW2_sp = (const float*)d_in[30];
    const float* eqb_sp  = (const float*)d_in[31];
    const float* aw_sp   = (const float*)d_in[32];
    const float* ab_sp   = (const float*)d_in[33];
    const float* nuW1  = (const float*)d_in[34];
    const float* nub1  = (const float*)d_in[35];
    const float* nuW2  = (const float*)d_in[36];
    const float* nub2  = (const float*)d_in[37];
    const float* nupW1 = (const float*)d_in[38];
    const float* nupb1 = (const float*)d_in[39];
    const float* nupW2 = (const float*)d_in[40];
    const float* nupb2 = (const float*)d_in[41];
    const float* p1W  = (const float*)d_in[42];
    const float* p1b  = (const float*)d_in[43];
    const float* p2aW = (const float*)d_in[44];
    const float* p2ab = (const float*)d_in[45];
    const float* p2bW = (const float*)d_in[46];
    const float* p2bb = (const float*)d_in[47];
    const float* p3W  = (const float*)d_in[48];
    const float* p3b  = (const float*)d_in[49];

    float* ws  = (float*)d_ws;
    float* out = (float*)d_out;

    k_step0<<<320, TPB, 0, stream>>>(
        sites, bonds, sites_p, bonds_sp, bonds_ps,
        idx1, idx2, idx1_ps, idx2_ps, idx1_sp, idx2_sp,
        se_W, se_b, sep_W, sep_b, ee_W, ee_b, eep_W, eep_b,
        eqW1_ss, eqW2_ss, eqb_ss, aw_ss, ab_ss,
        eqW1_ps, eqW2_ps, eqb_ps, aw_ps, ab_ps,
        eqW1_sp, eqW2_sp, eqb_sp, aw_sp, ab_sp,
        nuW1, nub1, nuW2, nub2, nupW1, nupb1, nupW2, nupb2, ws);
    for (int t = 1; t < TT; ++t) {
        k_step<<<320, TPB, 0, stream>>>(
            eqW1_ss, eqW2_ss, eqb_ss, aw_ss, ab_ss,
            eqW1_ps, eqW2_ps, eqb_ps, aw_ps, ab_ps,
            eqW1_sp, eqW2_sp, eqb_sp, aw_sp, ab_sp,
            idx1, idx1_ps, idx1_sp,
            nuW1, nub1, nuW2, nub2, nupW1, nupb1, nupW2, nupb2,
            p1W, p1b, p2aW, p2ab, p2bW, p2bb, p3W, p3b,
            ws, out, t);
    }
}

// Round 12
// 53.581 us; speedup vs baseline: 4.3467x; 1.9908x over previous
//
#include <hip/hip_runtime.h>
#include <math.h>

// ---- problem constants -------------------------------------------------
#define BB   4
#define NN   128
#define NPP  16
#define EEE  1280
#define ESP  1024
#define DD   32
#define CC   16
#define OO   32
#define FIN  80
#define MMM  64
#define TT   3
#define TPB  256

#define MAXDEG_SS 48
#define MAXDEG_SP 192

// ---- workspace layout (floats) ----------------------------------------
constexpr int OFF_S    = 0;
constexpr int OFF_SP   = OFF_S   + BB*NN*DD;
constexpr int OFF_BE   = OFF_SP  + BB*NPP*DD;
constexpr int OFF_BSP  = OFF_BE  + BB*EEE*CC;
constexpr int OFF_BPS  = OFF_BSP + BB*ESP*CC;
constexpr int OFF_PRJ  = OFF_BPS + BB*ESP*CC;
constexpr int P_SASS = 0;
constexpr int P_SBSS = P_SASS + BB*NN*OO;
constexpr int P_SBPS = P_SBSS + BB*NN*OO;
constexpr int P_SASP = P_SBPS + BB*NN*OO;
constexpr int P_PAPS = P_SASP + BB*NN*OO;
constexpr int P_PBSP = P_PAPS + BB*NPP*OO;
constexpr int PRJ_SZ = P_PBSP + BB*NPP*OO;
constexpr int OFF_POOL = OFF_PRJ + 2*PRJ_SZ;
constexpr int OFF_CSR  = OFF_POOL + BB*MMM;
// CSR int offsets (R7 layout):
constexpr int SS_CNT  = 0;
constexpr int SS_LIST = SS_CNT + NN;
constexpr int PS_CNT  = SS_LIST + NN*MAXDEG_SS;
constexpr int PS_LIST = PS_CNT + NN;
constexpr int SP_CNT  = PS_LIST + NN*MAXDEG_SS;
constexpr int SP_LIST = SP_CNT + NPP;
constexpr int CSR_INTS = SP_LIST + NPP*MAXDEG_SP;
constexpr int TICKET   = CSR_INTS;

__device__ __forceinline__ float lrelu(float x) { return x > 0.f ? x : 0.01f * x; }

__device__ __forceinline__ float dot16(const float* ef, const float* sWe, int o) {
    float4 f0 = *(const float4*)(ef);
    float4 f1 = *(const float4*)(ef + 4);
    float4 f2 = *(const float4*)(ef + 8);
    float4 f3 = *(const float4*)(ef + 12);
    return f0.x*sWe[ 0*32+o] + f0.y*sWe[ 1*32+o] + f0.z*sWe[ 2*32+o] + f0.w*sWe[ 3*32+o]
         + f1.x*sWe[ 4*32+o] + f1.y*sWe[ 5*32+o] + f1.z*sWe[ 6*32+o] + f1.w*sWe[ 7*32+o]
         + f2.x*sWe[ 8*32+o] + f2.y*sWe[ 9*32+o] + f2.z*sWe[10*32+o] + f2.w*sWe[11*32+o]
         + f3.x*sWe[12*32+o] + f3.y*sWe[13*32+o] + f3.z*sWe[14*32+o] + f3.w*sWe[15*32+o];
}

__device__ __forceinline__ float red32(float r) {
#pragma unroll
    for (int mm = 16; mm > 0; mm >>= 1) r += __shfl_xor(r, mm, 32);
    return r;
}

// ---- K0: step 0, self-sufficient with block-shared precompute ----------
// grid = 320 x 256: blocks 0..255 site receivers (2 each), 256..319 pores.
__global__ __launch_bounds__(TPB) void k_step0(
    const float* sites, const float* bonds, const float* sites_p,
    const float* bonds_sp, const float* bonds_ps,
    const int* idx1, const int* idx2, const int* idx1_ps, const int* idx2_ps,
    const int* idx1_sp, const int* idx2_sp,
    const float* se_W, const float* se_b, const float* sep_W, const float* sep_b,
    const float* ee_W, const float* ee_b, const float* eep_W, const float* eep_b,
    const float* eqW1_ss, const float* eqW2_ss, const float* eqb_ss, const float* aw_ss, const float* ab_ss,
    const float* eqW1_ps, const float* eqW2_ps, const float* eqb_ps, const float* aw_ps, const float* ab_ps,
    const float* eqW1_sp, const float* eqW2_sp, const float* eqb_sp, const float* aw_sp, const float* ab_sp,
    const float* nuW1, const float* nub1, const float* nuW2, const float* nub2,
    const float* nupW1, const float* nupb1, const float* nupW2, const float* nupb2,
    float* ws)
{
    __shared__ float sWA1[1024], sWA2[1024], sWB1[1024], sWB2[1024];  // 16KB
    __shared__ float sWE1[512], sWE2[512];                            // 4KB
    __shared__ float sS0[4096];                                       // 16KB batch site embeds
    __shared__ float sP0[512];                                        // 2KB batch pore embeds
    __shared__ float sEF[192*16];                                     // 12KB owned edge feats
    __shared__ int2  sLany[192];
    __shared__ int   sCnt[4];
    __shared__ float sRed[512], sH[192], sU[64], sSnew[64];

    const int tid = threadIdx.x, blk = blockIdx.x;
    const int slot = tid >> 5, o = tid & 31;
    int* csr = (int*)(ws + OFF_CSR);
    float* PRJn = ws + OFF_PRJ + 1 * PRJ_SZ;   // t=0 writes parity-1

    if (blk < 256) {
        // =============== site block: receivers g0=blk*2, g0+1 ===========
        const int b  = (blk*2) >> 7;
        const int n0 = (blk*2) & 127;
        // --- phase A: ballot scans (wave w -> list w): w0/w1 ss, w2/w3 ps
        {
            const int w = tid >> 6, lane = tid & 63;
            const int nw = n0 + (w & 1);
            const int* recvp = (w < 2) ? idx2 : idx2_ps;
            const int* sendp = (w < 2) ? idx1 : idx1_ps;
            const int Ew     = (w < 2) ? EEE : ESP;
            int2* ldst = sLany + w*48;
            int base = 0;
            for (int c = 0; c < Ew; c += 64) {
                const int e = c + lane;
                const bool m = (recvp[e] == nw);
                const unsigned long long mask = __ballot(m);
                if (m) {
                    const int pos = base + __popcll(mask & ((1ull << lane) - 1ull));
                    if (pos < MAXDEG_SS) {
                        ldst[pos] = make_int2(e, sendp[e]);
                        if (b == 0) {
                            if (w < 2) csr[SS_LIST + nw*MAXDEG_SS + pos] = e;
                            else       csr[PS_LIST + nw*MAXDEG_SS + pos] = e;
                        }
                    }
                }
                base += (int)__popcll(mask);
            }
            if (lane == 0) {
                int cc = base < MAXDEG_SS ? base : MAXDEG_SS;
                sCnt[w] = cc;
                if (b == 0) {
                    if (w < 2) csr[SS_CNT + nw] = cc;
                    else       csr[PS_CNT + nw] = cc;
                }
            }
        }
        // --- phase B1: stage weights + embeddings
        for (int i = tid; i < 1024; i += TPB) {
            sWA1[i] = eqW1_ss[i]        + eqW2_ss[i];
            sWB1[i] = eqW1_ss[1024 + i] + eqW2_ss[1024 + i];
            sWA2[i] = eqW1_ps[i]        + eqW2_ps[i];
            sWB2[i] = eqW1_ps[1024 + i] + eqW2_ps[1024 + i];
        }
        for (int i = tid; i < 512; i += TPB) {
            sWE1[i] = eqW1_ss[2048 + i] + eqW2_ss[2048 + i];
            sWE2[i] = eqW1_ps[2048 + i] + eqW2_ps[2048 + i];
        }
        for (int i = tid; i < 4096; i += TPB) {   // site embeddings, batch b
            const int n = i >> 5, oo = i & 31;
            sS0[i] = lrelu(sites[b*NN + n] * se_W[oo] + se_b[oo]);
        }
        for (int i = tid; i < 512; i += TPB) {    // pore embeddings, batch b
            const int p2 = i >> 5, oo = i & 31;
            sP0[i] = lrelu(sites_p[(b*NPP + p2)*2] * sep_W[oo]
                         + sites_p[(b*NPP + p2)*2 + 1] * sep_W[32 + oo] + sep_b[oo]);
        }
        __syncthreads();
        // --- phase B2: owned-edge features (also written to global)
        for (int i = tid; i < 192*16; i += TPB) {
            const int le = i >> 4, j = i & 15;
            const int w = le / 48, k = le - w*48;
            if (k < sCnt[w]) {
                const int e = sLany[w*48 + k].x;
                float bv; const float *W, *Bb;
                if (w < 2) { bv = bonds[b*EEE + e];    W = ee_W;  Bb = ee_b;  }
                else       { bv = bonds_ps[b*ESP + e]; W = eep_W; Bb = eep_b; }
                float a = Bb[j];
#pragma unroll
                for (int c = 0; c < 16; ++c) { float z = bv - (10.f/15.f)*c; a += expf(-z*z) * W[c*16 + j]; }
                a = lrelu(a);
                sEF[le*16 + j] = a;
                if (w < 2) ws[OFF_BE  + (b*EEE + e)*CC + j] = a;
                else       ws[OFF_BPS + (b*ESP + e)*CC + j] = a;
            }
        }
        __syncthreads();
        // --- phase C: edge loop (R7 grouping: r=slot>>2 receiver, q=slot&3)
        const int r = slot >> 2, q = slot & 3;
        const int nl = n0 + r;
        float sb_ss = 0.f, sb_ps = 0.f;
#pragma unroll
        for (int d = 0; d < 32; ++d) {
            const float sv = sS0[nl*32 + d];
            sb_ss += sv * sWB1[d*32 + o];
            sb_ps += sv * sWB2[d*32 + o];
        }
        float acc_ss = 0.f, acc_ps = 0.f;
        {
            const float bias = eqb_ss[o], awo = aw_ss[o], abv = ab_ss[0];
            const int cnt = sCnt[r];
            for (int k = q; k < cnt; k += 4) {
                const int2 es = sLany[r*48 + k];
                float SA = 0.f;
#pragma unroll
                for (int d = 0; d < 32; ++d) SA += sS0[es.y*32 + d] * sWA1[d*32 + o];
                float a = bias + sb_ss + SA + dot16(&sEF[(r*48 + k)*16], sWE1, o);
                float u = lrelu(a);
                float rr = red32(u * awo);
                acc_ss += u / (1.f + expf(-(rr + abv)));
            }
        }
        {
            const float bias = eqb_ps[o], awo = aw_ps[o], abv = ab_ps[0];
            const int cnt = sCnt[2 + r];
            for (int k = q; k < cnt; k += 4) {
                const int2 es = sLany[(2 + r)*48 + k];
                float SA = 0.f;
#pragma unroll
                for (int d = 0; d < 32; ++d) SA += sP0[es.y*32 + d] * sWA2[d*32 + o];
                float a = bias + sb_ps + SA + dot16(&sEF[((2 + r)*48 + k)*16], sWE2, o);
                float u = lrelu(a);
                float rr = red32(u * awo);
                acc_ps += u / (1.f + expf(-(rr + abv)));
            }
        }
        sRed[slot*64 + o]      = acc_ss;
        sRed[slot*64 + 32 + o] = acc_ps;
        if (tid < 64) sH[(tid>>5)*96 + (tid&31)] = sS0[(n0 + (tid>>5))*32 + (tid&31)];
        __syncthreads();
        if (tid < 128) {
            const int r2 = tid >> 6, c = tid & 63;
            sH[r2*96 + 32 + c] = sRed[(r2*4  )*64 + c] + sRed[(r2*4+1)*64 + c]
                               + sRed[(r2*4+2)*64 + c] + sRed[(r2*4+3)*64 + c];
        }
        __syncthreads();
        if (tid < 64) {
            const int r2 = tid >> 5, oo = tid & 31;
            float a = nub1[oo];
#pragma unroll
            for (int f = 0; f < 96; ++f) a += sH[r2*96 + f] * nuW1[f*32 + oo];
            sU[r2*32 + oo] = lrelu(a);
        }
        __syncthreads();
        if (tid < 64) {
            const int r2 = tid >> 5, oo = tid & 31;
            float a = nub2[oo];
#pragma unroll
            for (int k2 = 0; k2 < 32; ++k2) a += sU[r2*32 + k2] * nuW2[k2*32 + oo];
            const float snew = sH[r2*96 + oo] + lrelu(a);
            ws[OFF_S + (blk*2 + r2)*DD + oo] = snew;
            sSnew[r2*32 + oo] = snew;
        }
        __syncthreads();
        // epilogue: projections for step 1 (parity-1)
        {
            const int r2 = slot >> 2, m = slot & 3;
            const int g2 = blk*2 + r2;
            const float *w1m, *w2m; float* dst;
            if (m == 0)      { w1m = eqW1_ss + 1*FIN*OO;         w2m = eqW2_ss + 1*FIN*OO;         dst = PRJn + P_SASS; }
            else if (m == 1) { w1m = eqW1_ss + 1*FIN*OO + DD*OO; w2m = eqW2_ss + 1*FIN*OO + DD*OO; dst = PRJn + P_SBSS; }
            else if (m == 2) { w1m = eqW1_ps + 1*FIN*OO + DD*OO; w2m = eqW2_ps + 1*FIN*OO + DD*OO; dst = PRJn + P_SBPS; }
            else             { w1m = eqW1_sp + 1*FIN*OO;         w2m = eqW2_sp + 1*FIN*OO;         dst = PRJn + P_SASP; }
            float a = 0.f;
#pragma unroll
            for (int d = 0; d < 32; ++d) a += sSnew[r2*32 + d] * (w1m[d*OO + o] + w2m[d*OO + o]);
            dst[g2*OO + o] = a;
        }
    } else {
        // =============== pore block: receiver pg=blk-256 ================
        const int pg = blk - 256, b = pg >> 4, p = pg & 15;
        // --- scan (wave 0)
        if (tid < 64) {
            const int lane = tid;
            int base = 0;
            for (int c = 0; c < ESP; c += 64) {
                const int e = c + lane;
                const bool m = (idx2_sp[e] == p);
                const unsigned long long mask = __ballot(m);
                if (m) {
                    const int pos = base + __popcll(mask & ((1ull << lane) - 1ull));
                    if (pos < MAXDEG_SP) {
                        sLany[pos] = make_int2(e, idx1_sp[e]);
                        if (b == 0) csr[SP_LIST + p*MAXDEG_SP + pos] = e;
                    }
                }
                base += (int)__popcll(mask);
            }
            if (lane == 0) {
                int cc = base < MAXDEG_SP ? base : MAXDEG_SP;
                sCnt[0] = cc;
                if (b == 0) csr[SP_CNT + p] = cc;
            }
        }
        // --- stage weights + embeddings
        for (int i = tid; i < 1024; i += TPB) {
            sWA1[i] = eqW1_sp[i]        + eqW2_sp[i];
            sWB1[i] = eqW1_sp[1024 + i] + eqW2_sp[1024 + i];
        }
        for (int i = tid; i < 512; i += TPB)
            sWE1[i] = eqW1_sp[2048 + i] + eqW2_sp[2048 + i];
        for (int i = tid; i < 4096; i += TPB) {
            const int n = i >> 5, oo = i & 31;
            sS0[i] = lrelu(sites[b*NN + n] * se_W[oo] + se_b[oo]);
        }
        if (tid < 32)
            sP0[tid] = lrelu(sites_p[pg*2] * sep_W[tid]
                           + sites_p[pg*2 + 1] * sep_W[32 + tid] + sep_b[tid]);
        __syncthreads();
        // --- owned-edge features
        {
            const int cnt = sCnt[0];
            for (int i = tid; i < 192*16; i += TPB) {
                const int k = i >> 4, j = i & 15;
                if (k < cnt) {
                    const int e = sLany[k].x;
                    const float bv = bonds_sp[b*ESP + e];
                    float a = eep_b[j];
#pragma unroll
                    for (int c = 0; c < 16; ++c) { float z = bv - (10.f/15.f)*c; a += expf(-z*z) * eep_W[c*16 + j]; }
                    a = lrelu(a);
                    sEF[k*16 + j] = a;
                    ws[OFF_BSP + (b*ESP + e)*CC + j] = a;
                }
            }
        }
        __syncthreads();
        // --- edge loop (8 groups)
        float sb = 0.f;
#pragma unroll
        for (int d = 0; d < 32; ++d) sb += sP0[d] * sWB1[d*32 + o];
        const float bias = eqb_sp[o], awo = aw_sp[o], abv = ab_sp[0];
        const int cnt = sCnt[0];
        float acc = 0.f;
        for (int k = slot; k < cnt; k += 8) {
            const int2 es = sLany[k];
            float SA = 0.f;
#pragma unroll
            for (int d = 0; d < 32; ++d) SA += sS0[es.y*32 + d] * sWA1[d*32 + o];
            float a = bias + sb + SA + dot16(&sEF[k*16], sWE1, o);
            float u = lrelu(a);
            float rr = red32(u * awo);
            acc += u / (1.f + expf(-(rr + abv)));
        }
        sRed[slot*32 + o] = acc;
        if (tid < 32) sH[tid] = sP0[tid];
        __syncthreads();
        if (tid < 32) {
            float mv = 0.f;
#pragma unroll
            for (int s2 = 0; s2 < 8; ++s2) mv += sRed[s2*32 + tid];
            sH[32 + tid] = mv;
        }
        __syncthreads();
        if (tid < 32) {
            float a = nupb1[tid];
#pragma unroll
            for (int f = 0; f < 64; ++f) a += sH[f] * nupW1[f*32 + tid];
            sU[tid] = lrelu(a);
        }
        __syncthreads();
        if (tid < 32) {
            float a = nupb2[tid];
#pragma unroll
            for (int k2 = 0; k2 < 32; ++k2) a += sU[k2] * nupW2[k2*32 + tid];
            const float snew = sH[tid] + lrelu(a);
            ws[OFF_SP + pg*DD + tid] = snew;
            sSnew[tid] = snew;
        }
        __syncthreads();
        if (tid < 64) {
            const int m = slot, oo = tid & 31;
            const float *w1m, *w2m; float* dst;
            if (m == 0) { w1m = eqW1_ps + 1*FIN*OO;         w2m = eqW2_ps + 1*FIN*OO;         dst = PRJn + P_PAPS; }
            else        { w1m = eqW1_sp + 1*FIN*OO + DD*OO; w2m = eqW2_sp + 1*FIN*OO + DD*OO; dst = PRJn + P_PBSP; }
            float a = 0.f;
#pragma unroll
            for (int d = 0; d < 32; ++d) a += sSnew[d] * (w1m[d*OO + oo] + w2m[d*OO + oo]);
            dst[pg*OO + oo] = a;
        }
    }
}

// ---- K1: steps 1..2, verbatim R7 k_step (+pool/ticket zero at t==1) -----
__global__ __launch_bounds__(TPB) void k_step(
    const float* eqW1_ss, const float* eqW2_ss, const float* eqb_ss, const float* aw_ss, const float* ab_ss,
    const float* eqW1_ps, const float* eqW2_ps, const float* eqb_ps, const float* aw_ps, const float* ab_ps,
    const float* eqW1_sp, const float* eqW2_sp, const float* eqb_sp, const float* aw_sp, const float* ab_sp,
    const int* idx1, const int* idx1_ps, const int* idx1_sp,
    const float* nuW1, const float* nub1, const float* nuW2, const float* nub2,
    const float* nupW1, const float* nupb1, const float* nupW2, const float* nupb2,
    const float* p1W, const float* p1b,
    const float* p2aW, const float* p2ab, const float* p2bW, const float* p2bb,
    const float* p3W, const float* p3b,
    float* ws, float* out, int t)
{
    __shared__ float sWe1[512], sWe2[512], sRed[512], sH[192], sU[64], sSnew[64];
    __shared__ int sWin;
    const int tid = threadIdx.x, blk = blockIdx.x;
    const int slot = tid >> 5, o = tid & 31;
    const int par = t & 1;
    const float* PRJ  = ws + OFF_PRJ + par * PRJ_SZ;
    float*       PRJn = ws + OFF_PRJ + (par ^ 1) * PRJ_SZ;
    const int* csr = (const int*)(ws + OFF_CSR);

    if (t == 1 && blk == 0) {          // prep pool+ticket for t==2
        ws[OFF_POOL + tid] = 0.f;
        if (tid == 0) ((int*)(ws + OFF_CSR))[TICKET] = 0;
    }

    if (blk < 256) {
        const int r = slot >> 2, q = slot & 3;
        for (int i = tid; i < 512; i += TPB) {
            sWe1[i] = eqW1_ss[t*FIN*OO + 2*DD*OO + i] + eqW2_ss[t*FIN*OO + 2*DD*OO + i];
            sWe2[i] = eqW1_ps[t*FIN*OO + 2*DD*OO + i] + eqW2_ps[t*FIN*OO + 2*DD*OO + i];
        }
        __syncthreads();
        const int g = blk*2 + r, b = g >> 7, n = g & 127;
        const float bias_ss = eqb_ss[t*OO+o], awo_ss = aw_ss[t*OO+o], abs_ss = ab_ss[t];
        const float bias_ps = eqb_ps[t*OO+o], awo_ps = aw_ps[t*OO+o], abs_ps = ab_ps[t];
        const float sb_ss = PRJ[P_SBSS + g*OO + o];
        const float sb_ps = PRJ[P_SBPS + g*OO + o];
        const float* SAss = PRJ + P_SASS + b*(NN*OO);
        const float* PAps = PRJ + P_PAPS + b*(NPP*OO);
        const float* BEb  = ws + OFF_BE  + b*(EEE*CC);
        const float* BPSb = ws + OFF_BPS + b*(ESP*CC);
        float acc_ss = 0.f, acc_ps = 0.f;
        {
            const int cnt = csr[SS_CNT + n];
            const int* lst = csr + SS_LIST + n*MAXDEG_SS;
            for (int k = q; k < cnt; k += 4) {
                const int e = lst[k];
                const int s1 = idx1[e];
                float a = bias_ss + sb_ss + SAss[s1*OO + o] + dot16(BEb + e*CC, sWe1, o);
                float u = lrelu(a);
                float rr = red32(u * awo_ss);
                acc_ss += u / (1.f + expf(-(rr + abs_ss)));
            }
        }
        {
            const int cnt = csr[PS_CNT + n];
            const int* lst = csr + PS_LIST + n*MAXDEG_SS;
            for (int k = q; k < cnt; k += 4) {
                const int e = lst[k];
                const int s1 = idx1_ps[e];
                float a = bias_ps + sb_ps + PAps[s1*OO + o] + dot16(BPSb + e*CC, sWe2, o);
                float u = lrelu(a);
                float rr = red32(u * awo_ps);
                acc_ps += u / (1.f + expf(-(rr + abs_ps)));
            }
        }
        sRed[slot*64 + o]      = acc_ss;
        sRed[slot*64 + 32 + o] = acc_ps;
        if (tid < 64) sH[(tid>>5)*96 + (tid&31)] = ws[OFF_S + (blk*2 + (tid>>5))*DD + (tid&31)];
        __syncthreads();
        if (tid < 128) {
            const int r2 = tid >> 6, c = tid & 63;
            sH[r2*96 + 32 + c] = sRed[(r2*4  )*64 + c] + sRed[(r2*4+1)*64 + c]
                               + sRed[(r2*4+2)*64 + c] + sRed[(r2*4+3)*64 + c];
        }
        __syncthreads();
        if (tid < 64) {
            const int r2 = tid >> 5, oo = tid & 31;
            const float* W1 = nuW1 + t*(96*32);
            float a = nub1[t*32 + oo];
#pragma unroll
            for (int f = 0; f < 96; ++f) a += sH[r2*96 + f] * W1[f*32 + oo];
            sU[r2*32 + oo] = lrelu(a);
        }
        __syncthreads();
        if (tid < 64) {
            const int r2 = tid >> 5, oo = tid & 31;
            const float* W2 = nuW2 + t*(32*32);
            float a = nub2[t*32 + oo];
#pragma unroll
            for (int k2 = 0; k2 < 32; ++k2) a += sU[r2*32 + k2] * W2[k2*32 + oo];
            const float snew = sH[r2*96 + oo] + lrelu(a);
            ws[OFF_S + (blk*2 + r2)*DD + oo] = snew;
            sSnew[r2*32 + oo] = snew;
        }
        __syncthreads();
        if (t < TT-1) {
            const int r2 = slot >> 2, m = slot & 3;
            const int g2 = blk*2 + r2;
            const int tn = t + 1;
            const float *w1m, *w2m; float* dst;
            if (m == 0)      { w1m = eqW1_ss + tn*FIN*OO;         w2m = eqW2_ss + tn*FIN*OO;         dst = PRJn + P_SASS; }
            else if (m == 1) { w1m = eqW1_ss + tn*FIN*OO + DD*OO; w2m = eqW2_ss + tn*FIN*OO + DD*OO; dst = PRJn + P_SBSS; }
            else if (m == 2) { w1m = eqW1_ps + tn*FIN*OO + DD*OO; w2m = eqW2_ps + tn*FIN*OO + DD*OO; dst = PRJn + P_SBPS; }
            else             { w1m = eqW1_sp + tn*FIN*OO;         w2m = eqW2_sp + tn*FIN*OO;         dst = PRJn + P_SASP; }
            float a = 0.f;
#pragma unroll
            for (int d = 0; d < 32; ++d) a += sSnew[r2*32 + d] * (w1m[d*OO + o] + w2m[d*OO + o]);
            dst[g2*OO + o] = a;
        } else {
            if (tid < 128) {
                const int r2 = tid >> 6, mm = tid & 63;
                const int g2 = blk*2 + r2, b2 = g2 >> 7;
                float a = p1b[mm];
#pragma unroll
                for (int d = 0; d < 32; ++d) a += sSnew[r2*32 + d] * p1W[d*MMM + mm];
                atomicAdd(&ws[OFF_POOL + b2*MMM + mm], lrelu(a));
            }
            __syncthreads();
            if (tid == 0) {
                int* ticket = (int*)(ws + OFF_CSR) + TICKET;
                int p = __hip_atomic_fetch_add(ticket, 1, __ATOMIC_ACQ_REL, __HIP_MEMORY_SCOPE_AGENT);
                sWin = (p == 255) ? 1 : 0;
            }
            __syncthreads();
            if (sWin) {
                float* sx = sWe1;
                float* sy = sWe2;
                float* sz = sRed;
                sx[tid] = __hip_atomic_load(&ws[OFF_POOL + tid], __ATOMIC_RELAXED, __HIP_MEMORY_SCOPE_AGENT);
                __syncthreads();
                const int b2 = tid >> 6, mm = tid & 63;
                float a = p2ab[mm];
#pragma unroll
                for (int k = 0; k < MMM; ++k) a += sx[b2*64 + k] * p2aW[k*MMM + mm];
                sy[tid] = lrelu(a);
                __syncthreads();
                a = p2bb[mm];
#pragma unroll
                for (int k = 0; k < MMM; ++k) a += sy[b2*64 + k] * p2bW[k*MMM + mm];
                sz[tid] = lrelu(a);
                __syncthreads();
                if (tid < BB) {
                    float acc = p3b[0];
#pragma unroll
                    for (int k = 0; k < MMM; ++k) acc += sz[tid*64 + k] * p3W[k];
                    out[tid] = acc;
                }
            }
        }
    } else {
        for (int i = tid; i < 512; i += TPB)
            sWe1[i] = eqW1_sp[t*FIN*OO + 2*DD*OO + i] + eqW2_sp[t*FIN*OO + 2*DD*OO + i];
        __syncthreads();
        const int g = blk - 256, b = g >> 4, p = g & 15;
        const float bias_sp = eqb_sp[t*OO+o], awo_sp = aw_sp[t*OO+o], abs_sp = ab_sp[t];
        const float sb_sp = PRJ[P_PBSP + g*OO + o];
        const float* SAsp = PRJ + P_SASP + b*(NN*OO);
        const float* BSPb = ws + OFF_BSP + b*(ESP*CC);
        float acc_sp = 0.f;
        {
            const int cnt = csr[SP_CNT + p];
            const int* lst = csr + SP_LIST + p*MAXDEG_SP;
            for (int k = slot; k < cnt; k += 8) {
                const int e = lst[k];
                const int s1 = idx1_sp[e];
                float a = bias_sp + sb_sp + SAsp[s1*OO + o] + dot16(BSPb + e*CC, sWe1, o);
                float u = lrelu(a);
                float rr = red32(u * awo_sp);
                acc_sp += u / (1.f + expf(-(rr + abs_sp)));
            }
        }
        sRed[slot*32 + o] = acc_sp;
        if (tid < 32) sH[tid] = ws[OFF_SP + g*DD + tid];
        __syncthreads();
        if (tid < 32) {
            float mv = 0.f;
#pragma unroll
            for (int s2 = 0; s2 < 8; ++s2) mv += sRed[s2*32 + tid];
            sH[32 + tid] = mv;
        }
        __syncthreads();
        if (tid < 32) {
            const float* W1 = nupW1 + t*(64*32);
            float a = nupb1[t*32 + tid];
#pragma unroll
            for (int f = 0; f < 64; ++f) a += sH[f] * W1[f*32 + tid];
            sU[tid] = lrelu(a);
        }
        __syncthreads();
        if (tid < 32) {
            const float* W2 = nupW2 + t*(32*32);
            float a = nupb2[t*32 + tid];
#pragma unroll
            for (int k2 = 0; k2 < 32; ++k2) a += sU[k2] * W2[k2*32 + tid];
            const float snew = sH[tid] + lrelu(a);
            ws[OFF_SP + g*DD + tid] = snew;
            sSnew[tid] = snew;
        }
        __syncthreads();
        if (t < TT-1 && tid < 64) {
            const int tn = t + 1;
            const int m = tid >> 5, oo = tid & 31;
            const float *w1m, *w2m; float* dst;
            if (m == 0) { w1m = eqW1_ps + tn*FIN*OO;         w2m = eqW2_ps + tn*FIN*OO;         dst = PRJn + P_PAPS; }
            else        { w1m = eqW1_sp + tn*FIN*OO + DD*OO; w2m = eqW2_sp + tn*FIN*OO + DD*OO; dst = PRJn + P_PBSP; }
            float a = 0.f;
#pragma unroll
            for (int d = 0; d < 32; ++d) a += sSnew[d] * (w1m[d*OO + oo] + w2m[d*OO + oo]);
            dst[g*OO + oo] = a;
        }
    }
}

// ---- launch ------------------------------------------------------------
extern "C" void kernel_launch(void* const* d_in, const int* in_sizes, int n_in,
                              void* d_out, int out_size, void* d_ws, size_t ws_size,
                              hipStream_t stream) {
    (void)in_sizes; (void)n_in; (void)out_size; (void)ws_size;
    const float* sites    = (const float*)d_in[0];
    const float* bonds    = (const float*)d_in[1];
    const float* sites_p  = (const float*)d_in[2];
    const float* bonds_sp = (const float*)d_in[3];
    const float* bonds_ps = (const float*)d_in[4];
    const int* idx1    = (const int*)d_in[5];
    const int* idx2    = (const int*)d_in[6];
    const int* idx1_sp = (const int*)d_in[7];
    const int* idx2_sp = (const int*)d_in[8];
    const int* idx1_ps = (const int*)d_in[9];
    const int* idx2_ps = (const int*)d_in[10];
    const float* se_W  = (const float*)d_in[11];
    const float* se_b  = (const float*)d_in[12];
    const float* sep_W = (const float*)d_in[13];
    const float* sep_b = (const float*)d_in[14];
    const float* ee_W  = (const float*)d_in[15];
    const float* ee_b  = (const float*)d_in[16];
    const float* eep_W = (const float*)d_in[17];
    const float* eep_b = (const float*)d_in[18];
    const float* eqW1_ss = (const float*)d_in[19];
    const float* eqW2_ss = (const float*)d_in[20];
    const float* eqb_ss  = (const float*)d_in[21];
    const float* aw_ss   = (const float*)d_in[22];
    const float* ab_ss   = (const float*)d_in[23];
    const float* eqW1_ps = (const float*)d_in[24];
    const float* eqW2_ps = (const float*)d_in[25];
    const float* eqb_ps  = (const float*)d_in[26];
    const float* aw_ps   = (const float*)d_in[27];
    const float* ab_ps   = (const float*)d_in[28];
    const float* eqW1_sp = (const float*)d_in[29];
    const float* eqW2_sp = (const float*)d_in[30];
    const float* eqb_sp  = (const float*)d_in[31];
    const float* aw_sp   = (const float*)d_in[32];
    const float* ab_sp   = (const float*)d_in[33];
    const float* nuW1  = (const float*)d_in[34];
    const float* nub1  = (const float*)d_in[35];
    const float* nuW2  = (const float*)d_in[36];
    const float* nub2  = (const float*)d_in[37];
    const float* nupW1 = (const float*)d_in[38];
    const float* nupb1 = (const float*)d_in[39];
    const float* nupW2 = (const float*)d_in[40];
    const float* nupb2 = (const float*)d_in[41];
    const float* p1W  = (const float*)d_in[42];
    const float* p1b  = (const float*)d_in[43];
    const float* p2aW = (const float*)d_in[44];
    const float* p2ab = (const float*)d_in[45];
    const float* p2bW = (const float*)d_in[46];
    const float* p2bb = (const float*)d_in[47];
    const float* p3W  = (const float*)d_in[48];
    const float* p3b  = (const float*)d_in[49];

    float* ws  = (float*)d_ws;
    float* out = (float*)d_out;

    k_step0<<<320, TPB, 0, stream>>>(
        sites, bonds, sites_p, bonds_sp, bonds_ps,
        idx1, idx2, idx1_ps, idx2_ps, idx1_sp, idx2_sp,
        se_W, se_b, sep_W, sep_b, ee_W, ee_b, eep_W, eep_b,
        eqW1_ss, eqW2_ss, eqb_ss, aw_ss, ab_ss,
        eqW1_ps, eqW2_ps, eqb_ps, aw_ps, ab_ps,
        eqW1_sp, eqW2_sp, eqb_sp, aw_sp, ab_sp,
        nuW1, nub1, nuW2, nub2, nupW1, nupb1, nupW2, nupb2, ws);
    for (int t = 1; t < TT; ++t) {
        k_step<<<320, TPB, 0, stream>>>(
            eqW1_ss, eqW2_ss, eqb_ss, aw_ss, ab_ss,
            eqW1_ps, eqW2_ps, eqb_ps, aw_ps, ab_ps,
            eqW1_sp, eqW2_sp, eqb_sp, aw_sp, ab_sp,
            idx1, idx1_ps, idx1_sp,
            nuW1, nub1, nuW2, nub2, nupW1, nupb1, nupW2, nupb2,
            p1W, p1b, p2aW, p2ab, p2bW, p2bb, p3W, p3b,
            ws, out, t);
    }
}